// Round 1
// baseline (1849.286 us; speedup 1.0000x reference)
//
#include <hip/hip_runtime.h>
#include <math.h>

#define NTOK 100000
#define C 1024
#define SN 18
#define H 4
#define DH 256
#define HSN 72
#define CLAMPV 10000.0f
#define EPSV 1e-8f

__device__ __forceinline__ float sanitize_f(float v) {
    if (isnan(v)) return 0.0f;
    return fminf(CLAMPV, fmaxf(-CLAMPV, v));
}

__device__ __forceinline__ float waveSum(float v) {
    #pragma unroll
    for (int o = 32; o > 0; o >>= 1) v += __shfl_down(v, o, 64);
    return v;
}
__device__ __forceinline__ float waveMax(float v) {
    #pragma unroll
    for (int o = 32; o > 0; o >>= 1) v = fmaxf(v, __shfl_down(v, o, 64));
    return v;
}

// q = rmsnorm(seeds, w_nq); one block per seed row
__global__ void k_qnorm(const float* __restrict__ seeds, const float* __restrict__ w_nq,
                        float* __restrict__ q) {
    int row = blockIdx.x, tid = threadIdx.x;
    const float* src = seeds + (size_t)row * C;
    float ss = 0.f;
    for (int c = tid; c < C; c += 256) { float v = sanitize_f(src[c]); ss += v * v; }
    __shared__ float red[4]; __shared__ float sSc;
    float w = waveSum(ss);
    if ((tid & 63) == 0) red[tid >> 6] = w;
    __syncthreads();
    if (tid == 0) {
        float t = red[0] + red[1] + red[2] + red[3];
        float rms = sqrtf(t / (float)C);
        sSc = 1.0f / (rms + EPSV);
    }
    __syncthreads();
    float sc = sSc;
    for (int c = tid; c < C; c += 256) q[(size_t)row * C + c] = w_nq[c] * sanitize_f(src[c]) * sc;
}

// qp[s][j] = (q[s]·Wq[j] + bq[j]) / sqrt(Dh); one wave per output
__global__ void k_qp(const float* __restrict__ q, const float* __restrict__ Wq,
                     const float* __restrict__ bq, float* __restrict__ qp) {
    int tid = threadIdx.x, wid = tid >> 6, lane = tid & 63;
    int out = blockIdx.x * 4 + wid;          // < 18432
    int s = out >> 10, j = out & 1023;
    const float* qrow = q + (size_t)s * C;
    const float* wrow = Wq + (size_t)j * C;
    float acc = 0.f;
    #pragma unroll
    for (int k = 0; k < 16; ++k) { int c = lane + 64 * k; acc = fmaf(qrow[c], wrow[c], acc); }
    acc = waveSum(acc);
    if (lane == 0) qp[out] = (acc + bq[j]) * 0.0625f;
}

// Uw[hs][c] = (sum_d qp[s][h*DH+d] * Wk[h*DH+d][c]) * w_nkv[c];  hs = h*SN + s
__global__ void k_U(const float* __restrict__ qp, const float* __restrict__ in_proj_w,
                    const float* __restrict__ w_nkv, float* __restrict__ Uw) {
    int b = blockIdx.x, tid = threadIdx.x;
    int hs = b >> 2, ct = b & 3;
    int h = hs / SN, s = hs % SN;
    __shared__ float qps[DH];
    qps[tid] = qp[(size_t)s * C + h * DH + tid];
    __syncthreads();
    int c = ct * 256 + tid;
    const float* Wk = in_proj_w + (size_t)C * C;
    float acc = 0.f;
    #pragma unroll 4
    for (int d = 0; d < DH; ++d) acc = fmaf(qps[d], Wk[(size_t)(h * DH + d) * C + c], acc);
    Uw[(size_t)hs * C + c] = acc * w_nkv[c];
}

// bsc[hs] = qp[s,h,:]·bk[h,:]
__global__ void k_bsc(const float* __restrict__ qp, const float* __restrict__ in_proj_b,
                      float* __restrict__ bsc) {
    int tid = threadIdx.x, wid = tid >> 6, lane = tid & 63;
    int hs = blockIdx.x * 4 + wid;           // < 72
    int h = hs / SN, s = hs % SN;
    const float* bk = in_proj_b + C;
    float acc = 0.f;
    #pragma unroll
    for (int k = 0; k < 4; ++k) {
        int d = lane + 64 * k;
        acc = fmaf(qp[(size_t)s * C + h * DH + d], bk[h * DH + d], acc);
    }
    acc = waveSum(acc);
    if (lane == 0) bsc[hs] = acc;
}

// Pass A: per 64-row tile: sanitize x, rms scale, scores[hs][n] = scale_n*(Uw[hs]·t_n) + bsc[hs]
#define TST 132
__global__ __launch_bounds__(256, 4) void k_passA(const float* __restrict__ x,
    const float* __restrict__ Uw, const float* __restrict__ bsc,
    float* __restrict__ scaleG, float* __restrict__ scoresG) {
    __shared__ float tLds[64 * TST];
    __shared__ float bscLds[HSN];
    __shared__ float scaleLds[64];
    int tid = threadIdx.x;
    int n0 = blockIdx.x * 64;
    if (tid < HSN) bscLds[tid] = bsc[tid];
    int rg = tid & 31, hg = tid >> 5;
    float acc0[9], acc1[9];
    #pragma unroll
    for (int j = 0; j < 9; ++j) { acc0[j] = 0.f; acc1[j] = 0.f; }
    float ssReg[8];
    #pragma unroll
    for (int i = 0; i < 8; ++i) ssReg[i] = 0.f;

    for (int kt = 0; kt < 8; ++kt) {
        __syncthreads();
        #pragma unroll
        for (int i = 0; i < 8; ++i) {                 // stage 64x128 sanitized x tile
            int f = tid + 256 * i;
            int row = f >> 5, c4 = (f & 31) << 2;
            int n = n0 + row;
            float4 v = make_float4(0.f, 0.f, 0.f, 0.f);
            if (n < NTOK) v = *(const float4*)(x + (size_t)n * C + kt * 128 + c4);
            v.x = sanitize_f(v.x); v.y = sanitize_f(v.y);
            v.z = sanitize_f(v.z); v.w = sanitize_f(v.w);
            ssReg[i] += v.x * v.x + v.y * v.y + v.z * v.z + v.w * v.w;
            *(float4*)(tLds + row * TST + c4) = v;
        }
        __syncthreads();
        const float* Ub = Uw + (size_t)kt * 128;
        #pragma unroll 2
        for (int kk = 0; kk < 128; kk += 4) {
            float4 a0 = *(const float4*)(tLds + rg * TST + kk);
            float4 a1 = *(const float4*)(tLds + (rg + 32) * TST + kk);
            #pragma unroll
            for (int jj = 0; jj < 9; ++jj) {
                float4 u = *(const float4*)(Ub + (size_t)(hg * 9 + jj) * C + kk);
                acc0[jj] = fmaf(a0.x, u.x, fmaf(a0.y, u.y, fmaf(a0.z, u.z, fmaf(a0.w, u.w, acc0[jj]))));
                acc1[jj] = fmaf(a1.x, u.x, fmaf(a1.y, u.y, fmaf(a1.z, u.z, fmaf(a1.w, u.w, acc1[jj]))));
            }
        }
    }
    __syncthreads();
    // sumsq reduce: ssReg[i] belongs to row (tid>>5)+8i, 32 partials per row
    float* ssS = tLds;                                // reuse, stride 33
    #pragma unroll
    for (int i = 0; i < 8; ++i) ssS[((tid >> 5) + 8 * i) * 33 + (tid & 31)] = ssReg[i];
    __syncthreads();
    if (tid < 64) {
        float t = 0.f;
        #pragma unroll
        for (int k = 0; k < 32; ++k) t += ssS[tid * 33 + k];
        float rms = sqrtf(t / (float)C);
        float sc = 1.0f / (rms + EPSV);
        scaleLds[tid] = sc;
        if (n0 + tid < NTOK) scaleG[n0 + tid] = sc;
    }
    __syncthreads();
    #pragma unroll
    for (int jj = 0; jj < 9; ++jj) {
        int hs = hg * 9 + jj;
        float b = bscLds[hs];
        int n = n0 + rg;
        if (n < NTOK)      scoresG[(size_t)hs * NTOK + n]      = acc0[jj] * scaleLds[rg]      + b;
        if (n + 32 < NTOK) scoresG[(size_t)hs * NTOK + n + 32] = acc1[jj] * scaleLds[rg + 32] + b;
    }
}

// softmax stats per hs: max and sum of exp
__global__ void k_stats(const float* __restrict__ scoresG, float* __restrict__ mx,
                        float* __restrict__ denom) {
    int hs = blockIdx.x, tid = threadIdx.x;
    const float* row = scoresG + (size_t)hs * NTOK;
    float m = -INFINITY;
    for (int n = tid; n < NTOK; n += 256) m = fmaxf(m, row[n]);
    __shared__ float red[4]; __shared__ float sM;
    float w = waveMax(m);
    if ((tid & 63) == 0) red[tid >> 6] = w;
    __syncthreads();
    if (tid == 0) sM = fmaxf(fmaxf(red[0], red[1]), fmaxf(red[2], red[3]));
    __syncthreads();
    float mm = sM;
    float sum = 0.f;
    for (int n = tid; n < NTOK; n += 256) sum += __expf(row[n] - mm);
    __syncthreads();
    float ws2 = waveSum(sum);
    if ((tid & 63) == 0) red[tid >> 6] = ws2;
    __syncthreads();
    if (tid == 0) { mx[hs] = mm; denom[hs] = red[0] + red[1] + red[2] + red[3]; }
}

// Pass B: Praw[hs][c] += exp(score-max) * kv[n][c]  (kv without w_nkv; / denom applied later)
__global__ __launch_bounds__(256, 3) void k_passB(const float* __restrict__ x,
    const float* __restrict__ scoresG, const float* __restrict__ mx,
    const float* __restrict__ scaleG, float* __restrict__ Praw) {
    __shared__ float kvLds[64 * TST];
    __shared__ float wLds[64 * 73];
    __shared__ float mxLds[HSN];
    int tid = threadIdx.x;
    int ctile = blockIdx.x & 7;
    int chunk = blockIdx.x >> 3;                     // 98 chunks of 1024 rows
    int c0 = ctile * 128;
    if (tid < HSN) mxLds[tid] = mx[tid];
    int tc = tid & 31, hg = tid >> 5;
    float acc[9][4];
    #pragma unroll
    for (int j = 0; j < 9; ++j) { acc[j][0] = acc[j][1] = acc[j][2] = acc[j][3] = 0.f; }
    for (int scn = 0; scn < 16; ++scn) {
        int n0 = chunk * 1024 + scn * 64;
        __syncthreads();
        #pragma unroll
        for (int i = 0; i < 18; ++i) {               // stage softmax numerators 64x72
            int f = tid + 256 * i;                   // < 4608
            int hs = f >> 6, r = f & 63;
            int n = n0 + r;
            float wv = 0.f;
            if (n < NTOK) wv = __expf(scoresG[(size_t)hs * NTOK + n] - mxLds[hs]);
            wLds[r * 73 + hs] = wv;
        }
        #pragma unroll
        for (int i = 0; i < 8; ++i) {                // stage kv tile 64x128
            int f = tid + 256 * i;
            int row = f >> 5, c4 = (f & 31) << 2;
            int n = n0 + row;
            float4 v = make_float4(0.f, 0.f, 0.f, 0.f);
            if (n < NTOK) {
                v = *(const float4*)(x + (size_t)n * C + c0 + c4);
                float sc = scaleG[n];
                v.x = sanitize_f(v.x) * sc; v.y = sanitize_f(v.y) * sc;
                v.z = sanitize_f(v.z) * sc; v.w = sanitize_f(v.w) * sc;
            }
            *(float4*)(kvLds + row * TST + c4) = v;
        }
        __syncthreads();
        #pragma unroll 2
        for (int r = 0; r < 64; ++r) {
            float4 kv = *(const float4*)(kvLds + r * TST + tc * 4);
            #pragma unroll
            for (int jj = 0; jj < 9; ++jj) {
                float wv = wLds[r * 73 + hg * 9 + jj];
                acc[jj][0] = fmaf(wv, kv.x, acc[jj][0]);
                acc[jj][1] = fmaf(wv, kv.y, acc[jj][1]);
                acc[jj][2] = fmaf(wv, kv.z, acc[jj][2]);
                acc[jj][3] = fmaf(wv, kv.w, acc[jj][3]);
            }
        }
    }
    #pragma unroll
    for (int jj = 0; jj < 9; ++jj) {
        int hs = hg * 9 + jj;
        #pragma unroll
        for (int k = 0; k < 4; ++k)
            atomicAdd(Praw + (size_t)hs * C + c0 + tc * 4 + k, acc[jj][k]);
    }
}

// o[s][hd] = sum_c Wv[hd][c] * w_nkv[c] * Praw[hs][c] / denom[hs] + bv[hd]
__global__ void k_o(const float* __restrict__ Praw, const float* __restrict__ in_proj_w,
                    const float* __restrict__ in_proj_b, const float* __restrict__ w_nkv,
                    const float* __restrict__ denom, float* __restrict__ o) {
    int tid = threadIdx.x, wid = tid >> 6, lane = tid & 63;
    int out = blockIdx.x * 4 + wid;                  // < 18432
    int s = out >> 10, hd = out & 1023;
    int h = hd >> 8;
    int hs = h * SN + s;
    const float* Wv = in_proj_w + (size_t)2 * C * C + (size_t)hd * C;
    const float* P = Praw + (size_t)hs * C;
    float acc = 0.f;
    #pragma unroll
    for (int k = 0; k < 16; ++k) { int c = lane + 64 * k; acc = fmaf(Wv[c], w_nkv[c] * P[c], acc); }
    acc = waveSum(acc);
    if (lane == 0) o[(size_t)s * C + hd] = acc / denom[hs] + in_proj_b[2 * C + hd];
}

__global__ void k_obar(const float* __restrict__ o, float* __restrict__ obar) {
    int c = blockIdx.x * 256 + threadIdx.x;
    float acc = 0.f;
    #pragma unroll
    for (int s = 0; s < SN; ++s) acc += o[(size_t)s * C + c];
    obar[c] = acc * (1.0f / (float)SN);
}

// ctx[j] = sanitize(obar·Wout[j] + bout[j])
__global__ void k_out(const float* __restrict__ obar, const float* __restrict__ Wout,
                      const float* __restrict__ bout, float* __restrict__ outp) {
    int tid = threadIdx.x, wid = tid >> 6, lane = tid & 63;
    int j = blockIdx.x * 4 + wid;                    // < 1024
    float acc = 0.f;
    #pragma unroll
    for (int k = 0; k < 16; ++k) { int c = lane + 64 * k; acc = fmaf(obar[c], Wout[(size_t)j * C + c], acc); }
    acc = waveSum(acc);
    if (lane == 0) outp[j] = sanitize_f(acc + bout[j]);
}

extern "C" void kernel_launch(void* const* d_in, const int* in_sizes, int n_in,
                              void* d_out, int out_size, void* d_ws, size_t ws_size,
                              hipStream_t stream) {
    (void)in_sizes; (void)n_in; (void)out_size; (void)ws_size;
    const float* x         = (const float*)d_in[0];
    const float* seeds     = (const float*)d_in[1];
    const float* w_nq      = (const float*)d_in[2];
    const float* w_nkv     = (const float*)d_in[3];
    const float* in_proj_w = (const float*)d_in[4];
    const float* in_proj_b = (const float*)d_in[5];
    const float* out_proj_w = (const float*)d_in[6];
    const float* out_proj_b = (const float*)d_in[7];
    float* outp = (float*)d_out;

    float* ws     = (float*)d_ws;
    float* q      = ws;                  // 18432
    float* qp     = ws + 18432;          // 18432
    float* Uw     = ws + 36864;          // 73728
    float* bsc    = ws + 110592;         // 128
    float* mxA    = ws + 110720;         // 128
    float* den    = ws + 110848;         // 128
    float* scale  = ws + 110976;         // 100000
    float* scores = ws + 210976;         // 7200000
    float* Praw   = ws + 7410976;        // 73728
    float* o      = ws + 7484704;        // 18432
    float* obar   = ws + 7503136;        // 1024  (total 7504160 floats ~= 30 MB)

    k_qnorm<<<SN, 256, 0, stream>>>(seeds, w_nq, q);
    k_qp<<<4608, 256, 0, stream>>>(q, in_proj_w, in_proj_b, qp);
    k_U<<<HSN * 4, 256, 0, stream>>>(qp, in_proj_w, w_nkv, Uw);
    k_bsc<<<SN, 256, 0, stream>>>(qp, in_proj_b, bsc);
    k_passA<<<1563, 256, 0, stream>>>(x, Uw, bsc, scale, scores);
    k_stats<<<HSN, 256, 0, stream>>>(scores, mxA, den);
    hipMemsetAsync(Praw, 0, (size_t)HSN * C * sizeof(float), stream);
    k_passB<<<98 * 8, 256, 0, stream>>>(x, scores, mxA, scale, Praw);
    k_o<<<4608, 256, 0, stream>>>(Praw, in_proj_w, in_proj_b, w_nkv, den, o);
    k_obar<<<4, 256, 0, stream>>>(o, obar);
    k_out<<<256, 256, 0, stream>>>(obar, out_proj_w, out_proj_b, outp);
}

// Round 2
// 1354.911 us; speedup vs baseline: 1.3649x; 1.3649x over previous
//
#include <hip/hip_runtime.h>
#include <math.h>

#define NTOK 100000
#define C 1024
#define SN 18
#define H 4
#define DH 256
#define HSN 72
#define CLAMPV 10000.0f
#define EPSV 1e-8f

__device__ __forceinline__ float sanitize_f(float v) {
    if (isnan(v)) return 0.0f;
    return fminf(CLAMPV, fmaxf(-CLAMPV, v));
}

__device__ __forceinline__ float waveSum(float v) {
    #pragma unroll
    for (int o = 32; o > 0; o >>= 1) v += __shfl_down(v, o, 64);
    return v;
}
__device__ __forceinline__ float waveMax(float v) {
    #pragma unroll
    for (int o = 32; o > 0; o >>= 1) v = fmaxf(v, __shfl_down(v, o, 64));
    return v;
}

// q = rmsnorm(seeds, w_nq); one block per seed row
__global__ void k_qnorm(const float* __restrict__ seeds, const float* __restrict__ w_nq,
                        float* __restrict__ q) {
    int row = blockIdx.x, tid = threadIdx.x;
    const float* src = seeds + (size_t)row * C;
    float ss = 0.f;
    for (int c = tid; c < C; c += 256) { float v = sanitize_f(src[c]); ss += v * v; }
    __shared__ float red[4]; __shared__ float sSc;
    float w = waveSum(ss);
    if ((tid & 63) == 0) red[tid >> 6] = w;
    __syncthreads();
    if (tid == 0) {
        float t = red[0] + red[1] + red[2] + red[3];
        float rms = sqrtf(t / (float)C);
        sSc = 1.0f / (rms + EPSV);
    }
    __syncthreads();
    float sc = sSc;
    for (int c = tid; c < C; c += 256) q[(size_t)row * C + c] = w_nq[c] * sanitize_f(src[c]) * sc;
}

// qp[s][j] = (q[s]·Wq[j] + bq[j]) / sqrt(Dh); one wave per output
__global__ void k_qp(const float* __restrict__ q, const float* __restrict__ Wq,
                     const float* __restrict__ bq, float* __restrict__ qp) {
    int tid = threadIdx.x, wid = tid >> 6, lane = tid & 63;
    int out = blockIdx.x * 4 + wid;          // < 18432
    int s = out >> 10, j = out & 1023;
    const float* qrow = q + (size_t)s * C;
    const float* wrow = Wq + (size_t)j * C;
    float acc = 0.f;
    #pragma unroll
    for (int k = 0; k < 16; ++k) { int c = lane + 64 * k; acc = fmaf(qrow[c], wrow[c], acc); }
    acc = waveSum(acc);
    if (lane == 0) qp[out] = (acc + bq[j]) * 0.0625f;
}

// Uw[hs][c] = (sum_d qp[s][h*DH+d] * Wk[h*DH+d][c]) * w_nkv[c];  hs = h*SN + s
__global__ void k_U(const float* __restrict__ qp, const float* __restrict__ in_proj_w,
                    const float* __restrict__ w_nkv, float* __restrict__ Uw) {
    int b = blockIdx.x, tid = threadIdx.x;
    int hs = b >> 2, ct = b & 3;
    int h = hs / SN, s = hs % SN;
    __shared__ float qps[DH];
    qps[tid] = qp[(size_t)s * C + h * DH + tid];
    __syncthreads();
    int c = ct * 256 + tid;
    const float* Wk = in_proj_w + (size_t)C * C;
    float acc = 0.f;
    #pragma unroll 4
    for (int d = 0; d < DH; ++d) acc = fmaf(qps[d], Wk[(size_t)(h * DH + d) * C + c], acc);
    Uw[(size_t)hs * C + c] = acc * w_nkv[c];
}

// bsc[hs] = qp[s,h,:]·bk[h,:]
__global__ void k_bsc(const float* __restrict__ qp, const float* __restrict__ in_proj_b,
                      float* __restrict__ bsc) {
    int tid = threadIdx.x, wid = tid >> 6, lane = tid & 63;
    int hs = blockIdx.x * 4 + wid;           // < 72
    int h = hs / SN, s = hs % SN;
    const float* bk = in_proj_b + C;
    float acc = 0.f;
    #pragma unroll
    for (int k = 0; k < 4; ++k) {
        int d = lane + 64 * k;
        acc = fmaf(qp[(size_t)s * C + h * DH + d], bk[h * DH + d], acc);
    }
    acc = waveSum(acc);
    if (lane == 0) bsc[hs] = acc;
}

// Pass A: scores[hs][n] = scale_n*(Uw[hs]·x_san[n]) + bsc[hs]
// K chunked at 64; BOTH the x tile and the U k-slice staged in LDS.
#define XPAD 68
#define UPAD 68
__global__ __launch_bounds__(256, 4) void k_passA(const float* __restrict__ x,
    const float* __restrict__ Uw, const float* __restrict__ bsc,
    float* __restrict__ scaleG, float* __restrict__ scoresG) {
    __shared__ float xT[64 * XPAD];       // 17408 B
    __shared__ float uT[HSN * UPAD];      // 19584 B
    __shared__ float bscLds[HSN];
    __shared__ float scaleLds[64];
    int tid = threadIdx.x;
    int n0 = blockIdx.x * 64;
    if (tid < HSN) bscLds[tid] = bsc[tid];
    int rg = tid & 31, hg = tid >> 5;
    float acc0[9], acc1[9];
    #pragma unroll
    for (int j = 0; j < 9; ++j) { acc0[j] = 0.f; acc1[j] = 0.f; }
    float ss[4] = {0.f, 0.f, 0.f, 0.f};

    for (int kt = 0; kt < 16; ++kt) {
        __syncthreads();
        #pragma unroll
        for (int i = 0; i < 4; ++i) {                 // stage 64x64 sanitized x tile
            int f = tid + 256 * i;
            int row = f >> 4, c4 = (f & 15) << 2;
            int n = n0 + row;
            float4 v = make_float4(0.f, 0.f, 0.f, 0.f);
            if (n < NTOK) v = *(const float4*)(x + (size_t)n * C + kt * 64 + c4);
            v.x = sanitize_f(v.x); v.y = sanitize_f(v.y);
            v.z = sanitize_f(v.z); v.w = sanitize_f(v.w);
            ss[i] += v.x * v.x + v.y * v.y + v.z * v.z + v.w * v.w;
            *(float4*)(xT + row * XPAD + c4) = v;
        }
        #pragma unroll
        for (int i = 0; i < 5; ++i) {                 // stage 72x64 U slice
            int f = tid + 256 * i;
            if (f < 1152) {
                int row = f >> 4, c4 = (f & 15) << 2;
                *(float4*)(uT + row * UPAD + c4) =
                    *(const float4*)(Uw + (size_t)row * C + kt * 64 + c4);
            }
        }
        __syncthreads();
        #pragma unroll 4
        for (int kk = 0; kk < 64; kk += 4) {
            float4 a0 = *(const float4*)(xT + rg * XPAD + kk);
            float4 a1 = *(const float4*)(xT + (rg + 32) * XPAD + kk);
            #pragma unroll
            for (int jj = 0; jj < 9; ++jj) {
                float4 u = *(const float4*)(uT + (hg * 9 + jj) * UPAD + kk);
                acc0[jj] = fmaf(a0.x, u.x, fmaf(a0.y, u.y, fmaf(a0.z, u.z, fmaf(a0.w, u.w, acc0[jj]))));
                acc1[jj] = fmaf(a1.x, u.x, fmaf(a1.y, u.y, fmaf(a1.z, u.z, fmaf(a1.w, u.w, acc1[jj]))));
            }
        }
    }
    __syncthreads();
    // sumsq reduce: ss[i] belongs to row (tid+256i)>>4, 16 partials per row
    float* ssS = xT;                                  // reuse, stride 17
    #pragma unroll
    for (int i = 0; i < 4; ++i) ssS[((tid + 256 * i) >> 4) * 17 + (tid & 15)] = ss[i];
    __syncthreads();
    if (tid < 64) {
        float t = 0.f;
        #pragma unroll
        for (int k = 0; k < 16; ++k) t += ssS[tid * 17 + k];
        float rms = sqrtf(t / (float)C);
        float sc = 1.0f / (rms + EPSV);
        scaleLds[tid] = sc;
        if (n0 + tid < NTOK) scaleG[n0 + tid] = sc;
    }
    __syncthreads();
    #pragma unroll
    for (int jj = 0; jj < 9; ++jj) {
        int hs = hg * 9 + jj;
        float b = bscLds[hs];
        int n = n0 + rg;
        if (n < NTOK)      scoresG[(size_t)hs * NTOK + n]      = acc0[jj] * scaleLds[rg]      + b;
        if (n + 32 < NTOK) scoresG[(size_t)hs * NTOK + n + 32] = acc1[jj] * scaleLds[rg + 32] + b;
    }
}

// softmax stats stage 1: per (hs, chunk-of-6250): partial max + partial sum-exp
__global__ void k_stats1(const float* __restrict__ scoresG, float* __restrict__ pm,
                         float* __restrict__ pd) {
    int ch = blockIdx.x, hs = blockIdx.y, tid = threadIdx.x;
    int nbeg = ch * 6250, nend = nbeg + 6250;
    if (nend > NTOK) nend = NTOK;
    const float* row = scoresG + (size_t)hs * NTOK;
    float m = -INFINITY;
    for (int n = nbeg + tid; n < nend; n += 256) m = fmaxf(m, row[n]);
    __shared__ float red[4]; __shared__ float sM;
    float w = waveMax(m);
    if ((tid & 63) == 0) red[tid >> 6] = w;
    __syncthreads();
    if (tid == 0) sM = fmaxf(fmaxf(red[0], red[1]), fmaxf(red[2], red[3]));
    __syncthreads();
    float mm = sM;
    float sum = 0.f;
    for (int n = nbeg + tid; n < nend; n += 256) sum += __expf(row[n] - mm);
    __syncthreads();
    float ws2 = waveSum(sum);
    if ((tid & 63) == 0) red[tid >> 6] = ws2;
    __syncthreads();
    if (tid == 0) { pm[hs * 16 + ch] = mm; pd[hs * 16 + ch] = red[0] + red[1] + red[2] + red[3]; }
}

// stats stage 2: combine 16 chunks per hs
__global__ void k_stats2(const float* __restrict__ pm, const float* __restrict__ pd,
                         float* __restrict__ mx, float* __restrict__ den) {
    int t = threadIdx.x;
    if (t >= HSN) return;
    float m = -INFINITY;
    #pragma unroll
    for (int i = 0; i < 16; ++i) m = fmaxf(m, pm[t * 16 + i]);
    float s = 0.f;
    #pragma unroll
    for (int i = 0; i < 16; ++i) s += pd[t * 16 + i] * __expf(pm[t * 16 + i] - m);
    mx[t] = m; den[t] = s;
}

// w'[hs][n] = exp(score - mx) * scale_n / den   (in-place over scoresG)
__global__ void k_expw(float* __restrict__ scoresG, const float* __restrict__ mx,
                       const float* __restrict__ den, const float* __restrict__ scaleG) {
    int hs = blockIdx.y, tid = threadIdx.x;
    int n = (blockIdx.x * 256 + tid) * 4;
    float m = mx[hs], inv = 1.0f / den[hs];
    float* row = scoresG + (size_t)hs * NTOK;
    if (n + 3 < NTOK) {
        float4 s = *(const float4*)(row + n);
        float4 sc = *(const float4*)(scaleG + n);
        s.x = __expf(s.x - m) * sc.x * inv;
        s.y = __expf(s.y - m) * sc.y * inv;
        s.z = __expf(s.z - m) * sc.z * inv;
        s.w = __expf(s.w - m) * sc.w * inv;
        *(float4*)(row + n) = s;
    } else {
        for (int k = 0; k < 4; ++k)
            if (n + k < NTOK) row[n + k] = __expf(row[n + k] - m) * scaleG[n + k] * inv;
    }
}

// Pass B: Praw[hs][c] += w'[hs][n] * x_san[n][c]
#define TST 132
__global__ __launch_bounds__(256, 3) void k_passB(const float* __restrict__ x,
    const float* __restrict__ wG, float* __restrict__ Praw) {
    __shared__ float kvLds[64 * TST];
    __shared__ float wLds[64 * 73];
    int tid = threadIdx.x;
    int ctile = blockIdx.x & 7;
    int chunk = blockIdx.x >> 3;                     // 98 chunks of 1024 rows
    int c0 = ctile * 128;
    int tc = tid & 31, hg = tid >> 5;
    float acc[9][4];
    #pragma unroll
    for (int j = 0; j < 9; ++j) { acc[j][0] = acc[j][1] = acc[j][2] = acc[j][3] = 0.f; }
    for (int scn = 0; scn < 16; ++scn) {
        int n0 = chunk * 1024 + scn * 64;
        __syncthreads();
        #pragma unroll
        for (int i = 0; i < 18; ++i) {               // stage weights 64x72
            int f = tid + 256 * i;                   // < 4608
            int hs = f >> 6, r = f & 63;
            int n = n0 + r;
            float wv = 0.f;
            if (n < NTOK) wv = wG[(size_t)hs * NTOK + n];
            wLds[r * 73 + hs] = wv;
        }
        #pragma unroll
        for (int i = 0; i < 8; ++i) {                // stage x_san tile 64x128
            int f = tid + 256 * i;
            int row = f >> 5, c4 = (f & 31) << 2;
            int n = n0 + row;
            float4 v = make_float4(0.f, 0.f, 0.f, 0.f);
            if (n < NTOK) {
                v = *(const float4*)(x + (size_t)n * C + c0 + c4);
                v.x = sanitize_f(v.x); v.y = sanitize_f(v.y);
                v.z = sanitize_f(v.z); v.w = sanitize_f(v.w);
            }
            *(float4*)(kvLds + row * TST + c4) = v;
        }
        __syncthreads();
        #pragma unroll 2
        for (int r = 0; r < 64; ++r) {
            float4 kv = *(const float4*)(kvLds + r * TST + tc * 4);
            #pragma unroll
            for (int jj = 0; jj < 9; ++jj) {
                float wv = wLds[r * 73 + hg * 9 + jj];
                acc[jj][0] = fmaf(wv, kv.x, acc[jj][0]);
                acc[jj][1] = fmaf(wv, kv.y, acc[jj][1]);
                acc[jj][2] = fmaf(wv, kv.z, acc[jj][2]);
                acc[jj][3] = fmaf(wv, kv.w, acc[jj][3]);
            }
        }
    }
    #pragma unroll
    for (int jj = 0; jj < 9; ++jj) {
        int hs = hg * 9 + jj;
        #pragma unroll
        for (int k = 0; k < 4; ++k)
            atomicAdd(Praw + (size_t)hs * C + c0 + tc * 4 + k, acc[jj][k]);
    }
}

// o[s][hd] = sum_c Wv[hd][c] * w_nkv[c] * P[hs][c] + bv[hd]   (denom folded into w')
__global__ void k_o(const float* __restrict__ Praw, const float* __restrict__ in_proj_w,
                    const float* __restrict__ in_proj_b, const float* __restrict__ w_nkv,
                    float* __restrict__ o) {
    int tid = threadIdx.x, wid = tid >> 6, lane = tid & 63;
    int out = blockIdx.x * 4 + wid;                  // < 18432
    int s = out >> 10, hd = out & 1023;
    int h = hd >> 8;
    int hs = h * SN + s;
    const float* Wv = in_proj_w + (size_t)2 * C * C + (size_t)hd * C;
    const float* P = Praw + (size_t)hs * C;
    float acc = 0.f;
    #pragma unroll
    for (int k = 0; k < 16; ++k) { int c = lane + 64 * k; acc = fmaf(Wv[c], w_nkv[c] * P[c], acc); }
    acc = waveSum(acc);
    if (lane == 0) o[(size_t)s * C + hd] = acc + in_proj_b[2 * C + hd];
}

__global__ void k_obar(const float* __restrict__ o, float* __restrict__ obar) {
    int c = blockIdx.x * 256 + threadIdx.x;
    float acc = 0.f;
    #pragma unroll
    for (int s = 0; s < SN; ++s) acc += o[(size_t)s * C + c];
    obar[c] = acc * (1.0f / (float)SN);
}

// ctx[j] = sanitize(obar·Wout[j] + bout[j])
__global__ void k_out(const float* __restrict__ obar, const float* __restrict__ Wout,
                      const float* __restrict__ bout, float* __restrict__ outp) {
    int tid = threadIdx.x, wid = tid >> 6, lane = tid & 63;
    int j = blockIdx.x * 4 + wid;                    // < 1024
    float acc = 0.f;
    #pragma unroll
    for (int k = 0; k < 16; ++k) { int c = lane + 64 * k; acc = fmaf(obar[c], Wout[(size_t)j * C + c], acc); }
    acc = waveSum(acc);
    if (lane == 0) outp[j] = sanitize_f(acc + bout[j]);
}

extern "C" void kernel_launch(void* const* d_in, const int* in_sizes, int n_in,
                              void* d_out, int out_size, void* d_ws, size_t ws_size,
                              hipStream_t stream) {
    (void)in_sizes; (void)n_in; (void)out_size; (void)ws_size;
    const float* x         = (const float*)d_in[0];
    const float* seeds     = (const float*)d_in[1];
    const float* w_nq      = (const float*)d_in[2];
    const float* w_nkv     = (const float*)d_in[3];
    const float* in_proj_w = (const float*)d_in[4];
    const float* in_proj_b = (const float*)d_in[5];
    const float* out_proj_w = (const float*)d_in[6];
    const float* out_proj_b = (const float*)d_in[7];
    float* outp = (float*)d_out;

    float* ws     = (float*)d_ws;
    float* q      = ws;                  // 18432
    float* qp     = ws + 18432;          // 18432
    float* Uw     = ws + 36864;          // 73728
    float* bsc    = ws + 110592;         // 128
    float* mxA    = ws + 110720;         // 128
    float* den    = ws + 110848;         // 128
    float* scale  = ws + 110976;         // 100352
    float* pm     = ws + 211328;         // 1152
    float* pd     = ws + 212480;         // 1152
    float* scores = ws + 213632;         // 7200000 (becomes w' in place)
    float* Praw   = ws + 7413632;        // 73728
    float* o      = ws + 7487360;        // 18432
    float* obar   = ws + 7505792;        // 1024   (total ~30 MB)

    k_qnorm<<<SN, 256, 0, stream>>>(seeds, w_nq, q);
    k_qp<<<4608, 256, 0, stream>>>(q, in_proj_w, in_proj_b, qp);
    k_U<<<HSN * 4, 256, 0, stream>>>(qp, in_proj_w, w_nkv, Uw);
    k_bsc<<<SN, 256, 0, stream>>>(qp, in_proj_b, bsc);
    k_passA<<<1563, 256, 0, stream>>>(x, Uw, bsc, scale, scores);
    k_stats1<<<dim3(16, HSN), 256, 0, stream>>>(scores, pm, pd);
    k_stats2<<<1, 128, 0, stream>>>(pm, pd, mxA, den);
    k_expw<<<dim3(98, HSN), 256, 0, stream>>>(scores, mxA, den, scale);
    hipMemsetAsync(Praw, 0, (size_t)HSN * C * sizeof(float), stream);
    k_passB<<<98 * 8, 256, 0, stream>>>(x, scores, Praw);
    k_o<<<4608, 256, 0, stream>>>(Praw, in_proj_w, in_proj_b, w_nkv, o);
    k_obar<<<4, 256, 0, stream>>>(o, obar);
    k_out<<<256, 256, 0, stream>>>(obar, out_proj_w, out_proj_b, outp);
}

// Round 3
// 851.977 us; speedup vs baseline: 2.1706x; 1.5903x over previous
//
#include <hip/hip_runtime.h>
#include <math.h>

#define NTOK 100000
#define C 1024
#define SN 18
#define H 4
#define DH 256
#define HSN 72
#define CLAMPV 10000.0f
#define EPSV 1e-8f

using short8 = __attribute__((ext_vector_type(8))) short;
using f32x4  = __attribute__((ext_vector_type(4))) float;

__device__ __forceinline__ float sanitize_f(float v) {
    if (isnan(v)) return 0.0f;
    return fminf(CLAMPV, fmaxf(-CLAMPV, v));
}
__device__ __forceinline__ unsigned short f2bf(float f) {
    unsigned int u = __float_as_uint(f);
    u = (u + 0x7FFFu + ((u >> 16) & 1u)) >> 16;
    return (unsigned short)u;
}
__device__ __forceinline__ float waveSum(float v) {
    #pragma unroll
    for (int o = 32; o > 0; o >>= 1) v += __shfl_down(v, o, 64);
    return v;
}
__device__ __forceinline__ float waveMax(float v) {
    #pragma unroll
    for (int o = 32; o > 0; o >>= 1) v = fmaxf(v, __shfl_down(v, o, 64));
    return v;
}

// q = rmsnorm(seeds, w_nq); one block per seed row
__global__ void k_qnorm(const float* __restrict__ seeds, const float* __restrict__ w_nq,
                        float* __restrict__ q) {
    int row = blockIdx.x, tid = threadIdx.x;
    const float* src = seeds + (size_t)row * C;
    float ss = 0.f;
    for (int c = tid; c < C; c += 256) { float v = sanitize_f(src[c]); ss += v * v; }
    __shared__ float red[4]; __shared__ float sSc;
    float w = waveSum(ss);
    if ((tid & 63) == 0) red[tid >> 6] = w;
    __syncthreads();
    if (tid == 0) {
        float t = red[0] + red[1] + red[2] + red[3];
        float rms = sqrtf(t / (float)C);
        sSc = 1.0f / (rms + EPSV);
    }
    __syncthreads();
    float sc = sSc;
    for (int c = tid; c < C; c += 256) q[(size_t)row * C + c] = w_nq[c] * sanitize_f(src[c]) * sc;
}

// qp[s][j] = (q[s]·Wq[j] + bq[j]) / sqrt(Dh); one wave per output
__global__ void k_qp(const float* __restrict__ q, const float* __restrict__ Wq,
                     const float* __restrict__ bq, float* __restrict__ qp) {
    int tid = threadIdx.x, wid = tid >> 6, lane = tid & 63;
    int out = blockIdx.x * 4 + wid;          // < 18432
    int s = out >> 10, j = out & 1023;
    const float* qrow = q + (size_t)s * C;
    const float* wrow = Wq + (size_t)j * C;
    float acc = 0.f;
    #pragma unroll
    for (int k = 0; k < 16; ++k) { int c = lane + 64 * k; acc = fmaf(qrow[c], wrow[c], acc); }
    acc = waveSum(acc);
    if (lane == 0) qp[out] = (acc + bq[j]) * 0.0625f;
}

// Ub[row][c] = bf16( (sum_d qp[s][h*DH+d] * Wk[h*DH+d][c]) * w_nkv[c] );  row = h*SN+s, rows 72..79 = 0
__global__ void k_U(const float* __restrict__ qp, const float* __restrict__ in_proj_w,
                    const float* __restrict__ w_nkv, unsigned short* __restrict__ Ub) {
    int b = blockIdx.x, tid = threadIdx.x;
    int row = b >> 2, ct = b & 3;
    int c = ct * 256 + tid;
    __shared__ float qps[DH];
    if (row < HSN) {
        int h = row / SN, s = row % SN;
        qps[tid] = qp[(size_t)s * C + h * DH + tid];
        __syncthreads();
        const float* Wk = in_proj_w + (size_t)C * C;
        float acc = 0.f;
        #pragma unroll 4
        for (int d = 0; d < DH; ++d) acc = fmaf(qps[d], Wk[(size_t)(h * DH + d) * C + c], acc);
        Ub[(size_t)row * C + c] = f2bf(acc * w_nkv[c]);
    } else {
        Ub[(size_t)row * C + c] = 0;
    }
}

// bsc[hs] = qp[s,h,:]·bk[h,:]
__global__ void k_bsc(const float* __restrict__ qp, const float* __restrict__ in_proj_b,
                      float* __restrict__ bsc) {
    int tid = threadIdx.x, wid = tid >> 6, lane = tid & 63;
    int hs = blockIdx.x * 4 + wid;           // < 72
    int h = hs / SN, s = hs % SN;
    const float* bk = in_proj_b + C;
    float acc = 0.f;
    #pragma unroll
    for (int k = 0; k < 4; ++k) {
        int d = lane + 64 * k;
        acc = fmaf(qp[(size_t)s * C + h * DH + d], bk[h * DH + d], acc);
    }
    acc = waveSum(acc);
    if (lane == 0) bsc[hs] = acc;
}

// Pass A (MFMA): scores[hs][n] = scale_n * (U[hs]·x_san[n]) + bsc[hs]
// 128 tokens/block, K=1024 in 16 chunks of 64. A=U (m=hs), B=x_san (n=token), k=c.
__global__ __launch_bounds__(256, 3) void k_passA(const float* __restrict__ x,
    const unsigned short* __restrict__ Ub, const float* __restrict__ bsc,
    float* __restrict__ scaleG, float* __restrict__ scoresG) {
    __shared__ unsigned short xbL[8192];   // [ks2][tok128][c32]
    __shared__ unsigned short UbL[5120];   // [ks2][hs80][c32]
    __shared__ float bscLds[HSN];
    __shared__ float scaleLds[128];
    int tid = threadIdx.x;
    int n0 = blockIdx.x * 128;
    if (tid < HSN) bscLds[tid] = bsc[tid];
    int lane = tid & 63, wv = tid >> 6;
    int q = lane >> 4, mn = lane & 15;
    f32x4 acc[5][2];
    #pragma unroll
    for (int mt = 0; mt < 5; ++mt)
        #pragma unroll
        for (int nt = 0; nt < 2; ++nt) acc[mt][nt] = (f32x4){0.f, 0.f, 0.f, 0.f};
    float ss[8];
    #pragma unroll
    for (int i = 0; i < 8; ++i) ss[i] = 0.f;

    for (int kt = 0; kt < 16; ++kt) {
        __syncthreads();
        // stage x: 128 tok x 64 c, sanitize + bf16
        #pragma unroll
        for (int i = 0; i < 8; ++i) {
            int f = tid + 256 * i;           // 0..2047
            int tok = f >> 4, cq = f & 15;
            int n = n0 + tok;
            float4 v = make_float4(0.f, 0.f, 0.f, 0.f);
            if (n < NTOK) v = *(const float4*)(x + (size_t)n * C + kt * 64 + 4 * cq);
            v.x = sanitize_f(v.x); v.y = sanitize_f(v.y);
            v.z = sanitize_f(v.z); v.w = sanitize_f(v.w);
            ss[i] += v.x * v.x + v.y * v.y + v.z * v.z + v.w * v.w;
            unsigned int lo = (unsigned int)f2bf(v.x) | ((unsigned int)f2bf(v.y) << 16);
            unsigned int hi = (unsigned int)f2bf(v.z) | ((unsigned int)f2bf(v.w) << 16);
            int ks = cq >> 3, c32 = (cq & 7) * 4;
            *(uint2*)&xbL[ks * 4096 + tok * 32 + c32] = make_uint2(lo, hi);
        }
        // stage U: 80 rows x 64 c (bf16 copy)
        #pragma unroll
        for (int u = 0; u < 5; ++u) {
            int idx = tid + 256 * u;         // 0..1279
            int row = idx >> 4, cq = idx & 15;
            int ks = cq >> 3, c32 = (cq & 7) * 4;
            uint2 w4 = *(const uint2*)(Ub + (size_t)row * C + kt * 64 + 4 * cq);
            *(uint2*)&UbL[ks * 2560 + row * 32 + c32] = w4;
        }
        __syncthreads();
        #pragma unroll
        for (int ks = 0; ks < 2; ++ks) {
            short8 a[5], b[2];
            #pragma unroll
            for (int mt = 0; mt < 5; ++mt)
                a[mt] = *(const short8*)&UbL[ks * 2560 + (mt * 16 + mn) * 32 + q * 8];
            #pragma unroll
            for (int nt = 0; nt < 2; ++nt)
                b[nt] = *(const short8*)&xbL[ks * 4096 + (wv * 32 + nt * 16 + mn) * 32 + q * 8];
            #pragma unroll
            for (int mt = 0; mt < 5; ++mt)
                #pragma unroll
                for (int nt = 0; nt < 2; ++nt)
                    acc[mt][nt] = __builtin_amdgcn_mfma_f32_16x16x32_bf16(a[mt], b[nt], acc[mt][nt], 0, 0, 0);
        }
    }
    __syncthreads();
    // sumsq reduce: thread (tid) holds partial for token (tid>>4)+16i, 16 partials/token
    float* ssS = (float*)xbL;                // 128*17 floats = 8704 B, fits
    #pragma unroll
    for (int i = 0; i < 8; ++i) ssS[((tid >> 4) + 16 * i) * 17 + (tid & 15)] = ss[i];
    __syncthreads();
    if (tid < 128) {
        float t = 0.f;
        #pragma unroll
        for (int k = 0; k < 16; ++k) t += ssS[tid * 17 + k];
        float rms = sqrtf(t / (float)C);
        float sc = 1.0f / (rms + EPSV);
        scaleLds[tid] = sc;
        if (n0 + tid < NTOK) scaleG[n0 + tid] = sc;
    }
    __syncthreads();
    #pragma unroll
    for (int mt = 0; mt < 5; ++mt) {
        #pragma unroll
        for (int nt = 0; nt < 2; ++nt) {
            int tl = wv * 32 + nt * 16 + mn;
            int n = n0 + tl;
            #pragma unroll
            for (int r = 0; r < 4; ++r) {
                int hs = mt * 16 + q * 4 + r;
                if (hs < HSN && n < NTOK)
                    scoresG[(size_t)hs * NTOK + n] = acc[mt][nt][r] * scaleLds[tl] + bscLds[hs];
            }
        }
    }
}

// softmax stats stage 1: per (hs, chunk-of-6250): partial max + partial sum-exp
__global__ void k_stats1(const float* __restrict__ scoresG, float* __restrict__ pm,
                         float* __restrict__ pd) {
    int ch = blockIdx.x, hs = blockIdx.y, tid = threadIdx.x;
    int nbeg = ch * 6250, nend = nbeg + 6250;
    if (nend > NTOK) nend = NTOK;
    const float* row = scoresG + (size_t)hs * NTOK;
    float m = -INFINITY;
    for (int n = nbeg + tid; n < nend; n += 256) m = fmaxf(m, row[n]);
    __shared__ float red[4]; __shared__ float sM;
    float w = waveMax(m);
    if ((tid & 63) == 0) red[tid >> 6] = w;
    __syncthreads();
    if (tid == 0) sM = fmaxf(fmaxf(red[0], red[1]), fmaxf(red[2], red[3]));
    __syncthreads();
    float mm = sM;
    float sum = 0.f;
    for (int n = nbeg + tid; n < nend; n += 256) sum += __expf(row[n] - mm);
    __syncthreads();
    float ws2 = waveSum(sum);
    if ((tid & 63) == 0) red[tid >> 6] = ws2;
    __syncthreads();
    if (tid == 0) { pm[hs * 16 + ch] = mm; pd[hs * 16 + ch] = red[0] + red[1] + red[2] + red[3]; }
}

// stats stage 2: combine 16 chunks per hs
__global__ void k_stats2(const float* __restrict__ pm, const float* __restrict__ pd,
                         float* __restrict__ mx, float* __restrict__ den) {
    int t = threadIdx.x;
    if (t >= HSN) return;
    float m = -INFINITY;
    #pragma unroll
    for (int i = 0; i < 16; ++i) m = fmaxf(m, pm[t * 16 + i]);
    float s = 0.f;
    #pragma unroll
    for (int i = 0; i < 16; ++i) s += pd[t * 16 + i] * __expf(pm[t * 16 + i] - m);
    mx[t] = m; den[t] = s;
}

// Pass B (MFMA): Praw[hs][c] += sum_n w'[hs][n] * x_san[n][c],
// w' = exp(score-mx)*scale_n/den (computed during staging). A=w' (m=hs,k=tok), B=x_san^T (n=c,k=tok).
__global__ __launch_bounds__(256, 3) void k_passB(const float* __restrict__ x,
    const float* __restrict__ scoresG, const float* __restrict__ mx,
    const float* __restrict__ den, const float* __restrict__ scaleG,
    float* __restrict__ Praw) {
    __shared__ unsigned short xbTL[8192];   // [ks2][c128][tok32]
    __shared__ unsigned short wTL[5120];    // [ks2][hs80][tok32]
    __shared__ float mxL[80], idL[80], sL[64];
    int tid = threadIdx.x;
    // swizzle: all 8 c-tiles of one token-chunk land on one XCD (id mod 8 equal)
    int id = blockIdx.x;
    int r8 = id & 7, k8 = id >> 3;           // grid = 832
    int cb = k8 & 7;
    int tch = r8 + 8 * (k8 >> 3);
    if (tch >= 98) return;
    int c0 = cb * 128;
    if (tid < 80) {
        if (tid < HSN) { mxL[tid] = mx[tid]; idL[tid] = 1.0f / den[tid]; }
        else { mxL[tid] = 0.f; idL[tid] = 0.f; }
    }
    int lane = tid & 63, wv = tid >> 6;
    int q = lane >> 4, mn = lane & 15;
    f32x4 acc[5][2];
    #pragma unroll
    for (int mt = 0; mt < 5; ++mt)
        #pragma unroll
        for (int nt = 0; nt < 2; ++nt) acc[mt][nt] = (f32x4){0.f, 0.f, 0.f, 0.f};

    for (int scn = 0; scn < 16; ++scn) {
        int n0 = tch * 1024 + scn * 64;
        __syncthreads();
        if (tid < 16) *(float4*)&sL[tid * 4] = *(const float4*)(scaleG + n0 + tid * 4);
        __syncthreads();
        // stage w' tile: 80 hs x 64 tok (bf16)
        #pragma unroll
        for (int u = 0; u < 5; ++u) {
            int idx = tid + 256 * u;          // 0..1279
            int hs = idx >> 4, tq = idx & 15;
            int ks = tq >> 3, t32 = (tq & 7) * 4;
            int nbase = n0 + 4 * tq;
            unsigned int lo = 0, hi = 0;
            if (hs < HSN && nbase < NTOK) {
                float4 s4 = *(const float4*)(scoresG + (size_t)hs * NTOK + nbase);
                float mh = mxL[hs], ih = idL[hs];
                float w0 = __expf(s4.x - mh) * sL[4 * tq + 0] * ih;
                float w1 = __expf(s4.y - mh) * sL[4 * tq + 1] * ih;
                float w2 = __expf(s4.z - mh) * sL[4 * tq + 2] * ih;
                float w3 = __expf(s4.w - mh) * sL[4 * tq + 3] * ih;
                lo = (unsigned int)f2bf(w0) | ((unsigned int)f2bf(w1) << 16);
                hi = (unsigned int)f2bf(w2) | ((unsigned int)f2bf(w3) << 16);
            }
            *(uint2*)&wTL[ks * 2560 + hs * 32 + t32] = make_uint2(lo, hi);
        }
        // stage x^T tile: 128 c x 64 tok (bf16, transposed via registers)
        #pragma unroll
        for (int g = 0; g < 4; ++g) {
            int half = tid >> 7;              // = ks
            int cL = tid & 127;
            int tok0 = 32 * half + 8 * g;
            union { unsigned short u16[8]; short8 v; } pk;
            #pragma unroll
            for (int j = 0; j < 8; ++j) {
                int n = n0 + tok0 + j;
                float xv = 0.f;
                if (n < NTOK) xv = x[(size_t)n * C + c0 + cL];
                pk.u16[j] = f2bf(sanitize_f(xv));
            }
            *(short8*)&xbTL[half * 4096 + cL * 32 + 8 * g] = pk.v;
        }
        __syncthreads();
        #pragma unroll
        for (int ks = 0; ks < 2; ++ks) {
            short8 a[5], b[2];
            #pragma unroll
            for (int mt = 0; mt < 5; ++mt)
                a[mt] = *(const short8*)&wTL[ks * 2560 + (mt * 16 + mn) * 32 + q * 8];
            #pragma unroll
            for (int nt = 0; nt < 2; ++nt)
                b[nt] = *(const short8*)&xbTL[ks * 4096 + (wv * 32 + nt * 16 + mn) * 32 + q * 8];
            #pragma unroll
            for (int mt = 0; mt < 5; ++mt)
                #pragma unroll
                for (int nt = 0; nt < 2; ++nt)
                    acc[mt][nt] = __builtin_amdgcn_mfma_f32_16x16x32_bf16(a[mt], b[nt], acc[mt][nt], 0, 0, 0);
        }
    }
    #pragma unroll
    for (int mt = 0; mt < 5; ++mt) {
        #pragma unroll
        for (int r = 0; r < 4; ++r) {
            int hs = mt * 16 + q * 4 + r;
            if (hs < HSN) {
                #pragma unroll
                for (int nt = 0; nt < 2; ++nt) {
                    int cc = c0 + wv * 32 + nt * 16 + mn;
                    atomicAdd(Praw + (size_t)hs * C + cc, acc[mt][nt][r]);
                }
            }
        }
    }
}

// o[s][hd] = sum_c Wv[hd][c] * w_nkv[c] * P[hs][c] + bv[hd]   (denom folded into w')
__global__ void k_o(const float* __restrict__ Praw, const float* __restrict__ in_proj_w,
                    const float* __restrict__ in_proj_b, const float* __restrict__ w_nkv,
                    float* __restrict__ o) {
    int tid = threadIdx.x, wid = tid >> 6, lane = tid & 63;
    int out = blockIdx.x * 4 + wid;                  // < 18432
    int s = out >> 10, hd = out & 1023;
    int h = hd >> 8;
    int hs = h * SN + s;
    const float* Wv = in_proj_w + (size_t)2 * C * C + (size_t)hd * C;
    const float* P = Praw + (size_t)hs * C;
    float acc = 0.f;
    #pragma unroll
    for (int k = 0; k < 16; ++k) { int c = lane + 64 * k; acc = fmaf(Wv[c], w_nkv[c] * P[c], acc); }
    acc = waveSum(acc);
    if (lane == 0) o[(size_t)s * C + hd] = acc + in_proj_b[2 * C + hd];
}

__global__ void k_obar(const float* __restrict__ o, float* __restrict__ obar) {
    int c = blockIdx.x * 256 + threadIdx.x;
    float acc = 0.f;
    #pragma unroll
    for (int s = 0; s < SN; ++s) acc += o[(size_t)s * C + c];
    obar[c] = acc * (1.0f / (float)SN);
}

// ctx[j] = sanitize(obar·Wout[j] + bout[j])
__global__ void k_out(const float* __restrict__ obar, const float* __restrict__ Wout,
                      const float* __restrict__ bout, float* __restrict__ outp) {
    int tid = threadIdx.x, wid = tid >> 6, lane = tid & 63;
    int j = blockIdx.x * 4 + wid;                    // < 1024
    float acc = 0.f;
    #pragma unroll
    for (int k = 0; k < 16; ++k) { int c = lane + 64 * k; acc = fmaf(obar[c], Wout[(size_t)j * C + c], acc); }
    acc = waveSum(acc);
    if (lane == 0) outp[j] = sanitize_f(acc + bout[j]);
}

extern "C" void kernel_launch(void* const* d_in, const int* in_sizes, int n_in,
                              void* d_out, int out_size, void* d_ws, size_t ws_size,
                              hipStream_t stream) {
    (void)in_sizes; (void)n_in; (void)out_size; (void)ws_size;
    const float* x         = (const float*)d_in[0];
    const float* seeds     = (const float*)d_in[1];
    const float* w_nq      = (const float*)d_in[2];
    const float* w_nkv     = (const float*)d_in[3];
    const float* in_proj_w = (const float*)d_in[4];
    const float* in_proj_b = (const float*)d_in[5];
    const float* out_proj_w = (const float*)d_in[6];
    const float* out_proj_b = (const float*)d_in[7];
    float* outp = (float*)d_out;

    float* ws     = (float*)d_ws;
    float* q      = ws;                  // 18432
    float* qp     = ws + 18432;          // 18432
    unsigned short* Ub = (unsigned short*)(ws + 36864);  // 80*1024 bf16 = 40960 floats (slot 73728)
    float* bsc    = ws + 110592;         // 128
    float* mxA    = ws + 110720;         // 128
    float* den    = ws + 110848;         // 128
    float* scale  = ws + 110976;         // 100352
    float* pm     = ws + 211328;         // 1152
    float* pd     = ws + 212480;         // 1152
    float* scores = ws + 213632;         // 7200000
    float* Praw   = ws + 7413632;        // 73728
    float* o      = ws + 7487360;        // 18432
    float* obar   = ws + 7505792;        // 1024   (total ~30 MB)

    k_qnorm<<<SN, 256, 0, stream>>>(seeds, w_nq, q);
    k_qp<<<4608, 256, 0, stream>>>(q, in_proj_w, in_proj_b, qp);
    k_U<<<320, 256, 0, stream>>>(qp, in_proj_w, w_nkv, Ub);
    k_bsc<<<SN, 256, 0, stream>>>(qp, in_proj_b, bsc);
    k_passA<<<782, 256, 0, stream>>>(x, Ub, bsc, scale, scores);
    k_stats1<<<dim3(16, HSN), 256, 0, stream>>>(scores, pm, pd);
    k_stats2<<<1, 128, 0, stream>>>(pm, pd, mxA, den);
    hipMemsetAsync(Praw, 0, (size_t)HSN * C * sizeof(float), stream);
    k_passB<<<832, 256, 0, stream>>>(x, scores, mxA, den, scale, Praw);
    k_o<<<4608, 256, 0, stream>>>(Praw, in_proj_w, in_proj_b, w_nkv, o);
    k_obar<<<4, 256, 0, stream>>>(o, obar);
    k_out<<<256, 256, 0, stream>>>(obar, out_proj_w, out_proj_b, outp);
}